// Round 1
// baseline (57.211 us; speedup 1.0000x reference)
//
#include <hip/hip_runtime.h>

// B=64, N=1024 fixed by the problem; token_span is a runtime scalar input.
// start_position[b,i] = start[b,i] * max(end[b, i..min(i+span,N-1)])
// end_position[b,j]   = end[b,j]   * max(start[b, max(0,j-span)..j])
// Valid because all prob values are >= 0 (uniform [0,1)), so
// max over the banded outer-product row equals start * (window max of end),
// and the zeros outside the band never exceed it.

#define NCOLS 1024

__global__ __launch_bounds__(256) void banded_span_kernel(
    const float* __restrict__ prob,   // (B, 2N) row-major
    const int*   __restrict__ span_p, // scalar
    float* __restrict__ out,          // [B*N start_position | B*N end_position]
    int total)                        // B*N
{
    int idx = blockIdx.x * blockDim.x + threadIdx.x;
    if (idx >= total) return;

    const int span = *span_p;
    const int b = idx >> 10;          // / NCOLS
    const int k = idx & (NCOLS - 1);  // % NCOLS

    const float* row_start = prob + (size_t)b * (2 * NCOLS);
    const float* row_end   = row_start + NCOLS;

    // forward window max over end_prob
    float m_end = 0.0f;
    int jmax = k + span;
    if (jmax > NCOLS - 1) jmax = NCOLS - 1;
    #pragma unroll 4
    for (int j = k; j <= jmax; ++j) {
        m_end = fmaxf(m_end, row_end[j]);
    }

    // backward window max over start_prob
    float m_start = 0.0f;
    int imin = k - span;
    if (imin < 0) imin = 0;
    #pragma unroll 4
    for (int i = imin; i <= k; ++i) {
        m_start = fmaxf(m_start, row_start[i]);
    }

    out[idx]         = row_start[k] * m_end;   // start_position
    out[total + idx] = row_end[k]   * m_start; // end_position
}

extern "C" void kernel_launch(void* const* d_in, const int* in_sizes, int n_in,
                              void* d_out, int out_size, void* d_ws, size_t ws_size,
                              hipStream_t stream) {
    const float* prob = (const float*)d_in[0];
    const int* span   = (const int*)d_in[1];
    float* out        = (float*)d_out;

    const int total = in_sizes[0] / 2;  // B*N = 65536
    const int block = 256;
    const int grid  = (total + block - 1) / block;

    banded_span_kernel<<<grid, block, 0, stream>>>(prob, span, out, total);
}

// Round 2
// 56.553 us; speedup vs baseline: 1.0116x; 1.0116x over previous
//
#include <hip/hip_runtime.h>

// B=64, N=1024; token_span is a runtime scalar input (15 in the reference).
// start_position[b,i] = start[b,i] * max(end[b, i..min(i+span,N-1)])
// end_position[b,j]   = end[b,j]   * max(start[b, max(0,j-span)..j])
// Valid because prob >= 0 (uniform [0,1)): the banded outer-product row max
// factorizes into value * window-max, and the window always contains diff=0.
//
// Layout: one block per (row b, 256-col chunk c). Stage chunk+halo of both
// half-rows into LDS (coalesced, read input exactly once), then window maxes
// are stride-1 ds_read_b32 (2 lanes/bank on wave64 = conflict-free).

#define NCOLS 1024
#define CHUNK 256

__global__ __launch_bounds__(256) void banded_span_kernel(
    const float* __restrict__ prob,   // (B, 2N) row-major
    const int*   __restrict__ span_p, // scalar
    float* __restrict__ out)          // [B*N start_position | B*N end_position]
{
    // worst-case halo = NCOLS-CHUNK = 768 -> each array <= 1024 floats (8 KB total)
    __shared__ float s_start[NCOLS];  // [halo_l | chunk]
    __shared__ float s_end[NCOLS];    // [chunk | halo_r]

    const int span = *span_p;
    const int b    = blockIdx.x >> 2;        // / (NCOLS/CHUNK)
    const int c    = blockIdx.x & 3;
    const int col0 = c << 8;                 // * CHUNK
    const int t    = threadIdx.x;

    const float* row_start = prob + (size_t)b * (2 * NCOLS);
    const float* row_end   = row_start + NCOLS;

    const int halo_l = min(span, col0);                  // left halo (start row)
    const int halo_r = min(span, NCOLS - (col0 + CHUNK)); // right halo (end row)

    // s_start[i] = start[col0 - halo_l + i], i in [0, halo_l + CHUNK)
    for (int i = t; i < halo_l + CHUNK; i += CHUNK)
        s_start[i] = row_start[col0 - halo_l + i];
    // s_end[i] = end[col0 + i], i in [0, CHUNK + halo_r)
    for (int i = t; i < CHUNK + halo_r; i += CHUNK)
        s_end[i] = row_end[col0 + i];
    __syncthreads();

    const int k = col0 + t;                  // global column

    // forward window max over end_prob: j in [k, k+span] clamped to N-1
    const float ev = s_end[t];
    float m_end = ev;
    const int wr = min(span, (NCOLS - 1) - k);
    for (int j = 1; j <= wr; ++j)
        m_end = fmaxf(m_end, s_end[t + j]);

    // backward window max over start_prob: i in [k-span, k] clamped to 0
    const float sv = s_start[halo_l + t];
    float m_start = sv;
    const int wl = min(span, k);
    for (int i = 1; i <= wl; ++i)
        m_start = fmaxf(m_start, s_start[halo_l + t - i]);

    const int base = b * NCOLS + k;
    out[base]                 = sv * m_end;    // start_position
    out[64 * NCOLS + base]    = ev * m_start;  // end_position
}

extern "C" void kernel_launch(void* const* d_in, const int* in_sizes, int n_in,
                              void* d_out, int out_size, void* d_ws, size_t ws_size,
                              hipStream_t stream) {
    const float* prob = (const float*)d_in[0];
    const int* span   = (const int*)d_in[1];
    float* out        = (float*)d_out;

    const int B = in_sizes[0] / (2 * NCOLS);          // 64
    const int grid = B * (NCOLS / CHUNK);             // 256 blocks

    banded_span_kernel<<<grid, CHUNK, 0, stream>>>(prob, span, out);
}